// Round 15
// baseline (111.334 us; speedup 1.0000x reference)
//
#include <hip/hip_runtime.h>

// Masked causal MHA: B=2, S=2048, E=1024, H=16, D=64.
// ws layout (bf16/ushort): xb[4096*1024] | wqt|wkt|wvt|wot[1024*1024 each, [N][K]]
//   | Qh|Kh|Vh(unused) [b,h,s,d] | Vt [b,h,d,s] | Ob [4096][1024].

using f32x4  = __attribute__((ext_vector_type(4))) float;
using bf16x8 = __attribute__((ext_vector_type(8))) __bf16;
using u16x8  = __attribute__((ext_vector_type(8))) unsigned short;
using u32x4  = __attribute__((ext_vector_type(4))) unsigned int;

__device__ __forceinline__ unsigned short f2bf(float f) {
  unsigned u = __float_as_uint(f);
  u += 0x7fff + ((u >> 16) & 1u);            // round-to-nearest-even
  return (unsigned short)(u >> 16);
}

__device__ __forceinline__ unsigned short bfc(float f) {   // HW cvt
  __bf16 h = (__bf16)f;
  return __builtin_bit_cast(unsigned short, h);
}

__device__ __forceinline__ bf16x8 ld_bf8(const unsigned short* p) {
  return __builtin_bit_cast(bf16x8, *reinterpret_cast<const u16x8*>(p));
}

#define GLDS16(gp, lp)                                                        \
  __builtin_amdgcn_global_load_lds(                                           \
      (__attribute__((address_space(1))) void*)(gp),                          \
      (__attribute__((address_space(3))) void*)(lp), 16, 0, 0)

// ------------------------------------------- prep: cast x + transpose weights
// blocks 0..4095: cast x -> bf16. blocks 4096..5119: W[k][n] -> Wt[n][k] bf16.
__global__ void prep_kernel(const float* __restrict__ x,
                            const float* __restrict__ w0, const float* __restrict__ w1,
                            const float* __restrict__ w2, const float* __restrict__ w3,
                            unsigned short* __restrict__ xb,
                            unsigned short* __restrict__ t0, unsigned short* __restrict__ t1,
                            unsigned short* __restrict__ t2, unsigned short* __restrict__ t3) {
  __shared__ float tile[64][65];
  const int t = threadIdx.x;
  const int bid = blockIdx.x;
  if (bid < 4096) {
    const int i = (bid * 256 + t) * 4;
    const float4 v = *reinterpret_cast<const float4*>(x + i);
    ushort4 o;
    o.x = f2bf(v.x); o.y = f2bf(v.y); o.z = f2bf(v.z); o.w = f2bf(v.w);
    *reinterpret_cast<ushort4*>(xb + i) = o;
    return;
  }
  const int q0 = bid - 4096;
  const int wsel = q0 >> 8, rem = q0 & 255;
  const float* src; unsigned short* dst;
  switch (wsel) {
    case 0:  src = w0; dst = t0; break;
    case 1:  src = w1; dst = t1; break;
    case 2:  src = w2; dst = t2; break;
    default: src = w3; dst = t3; break;
  }
  const int n0 = (rem & 15) * 64, k0 = (rem >> 4) * 64;
#pragma unroll
  for (int i = 0; i < 4; ++i) {               // load 64x64 fp32 tile, rows = k
    const int q = t + i * 256, r = q >> 4, c4 = q & 15;
    const float4 v = *reinterpret_cast<const float4*>(src + (k0 + r) * 1024 + n0 + c4 * 4);
    tile[r][c4 * 4 + 0] = v.x; tile[r][c4 * 4 + 1] = v.y;
    tile[r][c4 * 4 + 2] = v.z; tile[r][c4 * 4 + 3] = v.w;
  }
  __syncthreads();
#pragma unroll
  for (int i = 0; i < 4; ++i) {               // write Wt[n][k] bf16
    const int q = t + i * 256, n = q >> 4, c4 = q & 15;
    ushort4 o;
    o.x = f2bf(tile[c4 * 4 + 0][n]); o.y = f2bf(tile[c4 * 4 + 1][n]);
    o.z = f2bf(tile[c4 * 4 + 2][n]); o.w = f2bf(tile[c4 * 4 + 3][n]);
    *reinterpret_cast<ushort4*>(dst + (n0 + n) * 1024 + k0 + c4 * 4) = o;
  }
}

// ------------------------------------------------------------ QKV GEMM
// C[4096][N] = xb @ Wt^T (+ bias). 128x128 tile, BK=64, 4 waves of 64x64.
// Q scaled by 0.125*log2e -> [b,h,s,d]; K -> [b,h,s,d]; V -> Vt [b,h,d,s].
__global__ __launch_bounds__(256, 3) void gemm_qkv(
    const unsigned short* __restrict__ A,
    const unsigned short* __restrict__ BtQ, const unsigned short* __restrict__ BtK,
    const unsigned short* __restrict__ BtV,
    const float* __restrict__ biasQ, const float* __restrict__ biasK,
    const float* __restrict__ biasV,
    unsigned short* __restrict__ OQ, unsigned short* __restrict__ OK_,
    unsigned short* __restrict__ OVt) {
  __shared__ unsigned short As[128 * 64];
  __shared__ unsigned short Bs[128 * 64];

  const int mt = blockIdx.x, nt = blockIdx.y;
  const int which = nt >> 3;
  const int nloc0 = (nt & 7) * 128;
  const unsigned short* Bt = (which == 0) ? BtQ : (which == 1) ? BtK : BtV;
  const float* bias = (which == 0) ? biasQ : (which == 1) ? biasK : biasV;
  const int m0 = mt * 128;
  const int t = threadIdx.x;
  const int w = t >> 6, l = t & 63;
  const int wm = (w >> 1) * 64, wn = (w & 1) * 64;
  const int lr = l & 15, lg = l >> 4;

  f32x4 acc[4][4];
#pragma unroll
  for (int i = 0; i < 4; ++i)
#pragma unroll
    for (int j = 0; j < 4; ++j) acc[i][j] = f32x4{0.f, 0.f, 0.f, 0.f};

  for (int k0 = 0; k0 < 1024; k0 += 64) {
#pragma unroll
    for (int i = 0; i < 4; ++i) {             // stage A tile: [128 m][64 k]
      const int off = t * 16 + i * 4096;
      const int r = off >> 7, cb = off & 127;
      GLDS16(A + (m0 + r) * 1024 + k0 + (cb >> 1), ((char*)As) + off);
    }
#pragma unroll
    for (int i = 0; i < 4; ++i) {             // stage B tile: [128 n][64 k]
      const int off = t * 16 + i * 4096;
      const int r = off >> 7, cb = off & 127;
      GLDS16(Bt + (nloc0 + r) * 1024 + k0 + (cb >> 1), ((char*)Bs) + off);
    }
    __syncthreads();
#pragma unroll
    for (int kk = 0; kk < 2; ++kk) {
      bf16x8 af[4], bfr[4];
#pragma unroll
      for (int mi = 0; mi < 4; ++mi)
        af[mi] = ld_bf8(As + (wm + mi * 16 + lr) * 64 + kk * 32 + lg * 8);
#pragma unroll
      for (int ni = 0; ni < 4; ++ni)
        bfr[ni] = ld_bf8(Bs + (wn + ni * 16 + lr) * 64 + kk * 32 + lg * 8);
#pragma unroll
      for (int mi = 0; mi < 4; ++mi)
#pragma unroll
        for (int ni = 0; ni < 4; ++ni)
          acc[mi][ni] = __builtin_amdgcn_mfma_f32_16x16x32_bf16(af[mi], bfr[ni], acc[mi][ni], 0, 0, 0);
    }
    __syncthreads();
  }

  const float scl = (which == 0) ? 0.18033688f : 1.0f;   // 0.125*log2(e) for Q
#pragma unroll
  for (int ni = 0; ni < 4; ++ni) {
    const int n = nloc0 + wn + ni * 16 + lr;  // column within this weight
    const float bv = bias[n];
    const int hh = n >> 6, dd = n & 63;
#pragma unroll
    for (int mi = 0; mi < 4; ++mi) {
      const int mB = m0 + wm + mi * 16 + 4 * lg;
      const int bb = mB >> 11, sloc = mB & 2047;
      if (which == 2) {                       // V -> Vt [b,h,d,s], 8B stores
        ushort4 o4;
        o4.x = bfc(acc[mi][ni][0] + bv);
        o4.y = bfc(acc[mi][ni][1] + bv);
        o4.z = bfc(acc[mi][ni][2] + bv);
        o4.w = bfc(acc[mi][ni][3] + bv);
        *reinterpret_cast<ushort4*>(
            &OVt[(((size_t)(bb * 16 + hh)) * 64 + dd) * 2048 + sloc]) = o4;
      } else {
        unsigned short* Oqk = (which == 0) ? OQ : OK_;
#pragma unroll
        for (int r = 0; r < 4; ++r) {
          const float v = (acc[mi][ni][r] + bv) * scl;
          Oqk[(((size_t)(bb * 16 + hh)) * 2048 + sloc + r) * 64 + dd] = f2bf(v);
        }
      }
    }
  }
}

// ------------------------------------------------------- output-proj GEMM
// C[4096][1024] = Ob @ Wot^T + bo (fp32). 64x128 tile -> 512 blocks (2/CU).
__global__ __launch_bounds__(256, 2) void gemm_out(
    const unsigned short* __restrict__ A, const unsigned short* __restrict__ Bt,
    const float* __restrict__ bias, float* __restrict__ OF) {
  __shared__ unsigned short As[64 * 64];     // 8 KB
  __shared__ unsigned short Bs[128 * 64];    // 16 KB

  const int m0 = blockIdx.x * 64;
  const int nloc0 = blockIdx.y * 128;
  const int t = threadIdx.x;
  const int w = t >> 6, l = t & 63;
  const int wm = (w >> 1) * 32, wn = (w & 1) * 64;
  const int lr = l & 15, lg = l >> 4;

  f32x4 acc[2][4];
#pragma unroll
  for (int i = 0; i < 2; ++i)
#pragma unroll
    for (int j = 0; j < 4; ++j) acc[i][j] = f32x4{0.f, 0.f, 0.f, 0.f};

  for (int k0 = 0; k0 < 1024; k0 += 64) {
#pragma unroll
    for (int i = 0; i < 2; ++i) {             // stage A tile: [64 m][64 k]
      const int off = t * 16 + i * 4096;
      const int r = off >> 7, cb = off & 127;
      GLDS16(A + (m0 + r) * 1024 + k0 + (cb >> 1), ((char*)As) + off);
    }
#pragma unroll
    for (int i = 0; i < 4; ++i) {             // stage B tile: [128 n][64 k]
      const int off = t * 16 + i * 4096;
      const int r = off >> 7, cb = off & 127;
      GLDS16(Bt + (nloc0 + r) * 1024 + k0 + (cb >> 1), ((char*)Bs) + off);
    }
    __syncthreads();
#pragma unroll
    for (int kk = 0; kk < 2; ++kk) {
      bf16x8 af[2], bfr[4];
#pragma unroll
      for (int mi = 0; mi < 2; ++mi)
        af[mi] = ld_bf8(As + (wm + mi * 16 + lr) * 64 + kk * 32 + lg * 8);
#pragma unroll
      for (int ni = 0; ni < 4; ++ni)
        bfr[ni] = ld_bf8(Bs + (wn + ni * 16 + lr) * 64 + kk * 32 + lg * 8);
#pragma unroll
      for (int mi = 0; mi < 2; ++mi)
#pragma unroll
        for (int ni = 0; ni < 4; ++ni)
          acc[mi][ni] = __builtin_amdgcn_mfma_f32_16x16x32_bf16(af[mi], bfr[ni], acc[mi][ni], 0, 0, 0);
    }
    __syncthreads();
  }

#pragma unroll
  for (int ni = 0; ni < 4; ++ni) {
    const int n = nloc0 + wn + ni * 16 + lr;
    const float bv = bias[n];
#pragma unroll
    for (int mi = 0; mi < 2; ++mi) {
#pragma unroll
      for (int r = 0; r < 4; ++r) {
        const int m = m0 + wm + mi * 16 + 4 * lg + r;
        OF[m * 1024 + n] = acc[mi][ni][r] + bv;
      }
    }
  }
}

// ------------------------------------------------------ flash attention v11
// R9's proven body with ONE sync-structure change (T4): 3-slot LDS ring,
// stage distance 2, counted s_waitcnt vmcnt(4) + raw s_barrier instead of
// __syncthreads — prefetch loads span a full iteration. lgkmcnt(0) at the
// barrier preserves the vbp-read-before-slot-reuse guarantee. 48 KB LDS ->
// 3 blocks/CU; 256 queued blocks give natural LPT tail balancing.
__global__ __launch_bounds__(256, 3) void attn_kernel(
    const unsigned short* __restrict__ Qh, const unsigned short* __restrict__ Kh,
    const unsigned short* __restrict__ Vt, unsigned short* __restrict__ Ob) {
  const int g = blockIdx.x;
  const int qt = 31 - (g >> 5);              // LPT: longest first
  const int bh = g & 31;
  const int b = bh >> 4, h = bh & 15;
  const int t = threadIdx.x, w = t >> 6, l = t & 63;
  const int lr = l & 15, lg = l >> 4;
  const int sl0 = lr + 32 * (lg & 1);        // pack-shuffle source lanes
  const int sl1 = sl0 + 16;
  const bool hi2 = (l & 32) != 0;

  __shared__ unsigned short Kb[3][4096];     // [64 kv][64 d], swizzled
  __shared__ unsigned short Vb[3][4096];     // [64 d][64 kv], swizzled

  const unsigned short* Kbase = Kh + (size_t)bh * (2048 * 64);
  const unsigned short* Vbase = Vt + (size_t)bh * (64 * 2048);

  const int qb = qt * 64 + w * 16;           // this wave's 16 q rows
  const unsigned short* Qp = Qh + ((size_t)bh * 2048 + qb + lr) * 64;
  bf16x8 qf[2];
  qf[0] = ld_bf8(Qp + lg * 8);
  qf[1] = ld_bf8(Qp + 32 + lg * 8);

  f32x4 oacc[4];                             // O^T: lane q=qb+lr, d=df*16+4lg+r
#pragma unroll
  for (int i = 0; i < 4; ++i) oacc[i] = f32x4{0.f, 0.f, 0.f, 0.f};
  float mrun = -3e38f;
  float lpart = 0.f;                         // per-lane partial denominator

  bf16x8 vbp[2][4];                          // V frags of previous tile
  bf16x8 pap[2];                             // P frags of previous tile

  auto stage = [&](int kv0, int bi) {        // 4 loads/thread (2 K + 2 V)
#pragma unroll
    for (int p = 0; p < 2; ++p) {
      const int o = t * 16 + p * 4096;       // linear byte offset in 8KB tile
      const int row = o >> 7;
      const int scb = (o & 127) ^ ((row & 7) << 4);   // pre-swizzled src col
      GLDS16(Kbase + (size_t)(kv0 + row) * 64 + (scb >> 1), ((char*)Kb[bi]) + o);
      GLDS16(Vbase + (size_t)row * 2048 + kv0 + (scb >> 1), ((char*)Vb[bi]) + o);
    }
  };

  const int nt = qt + 1;
  stage(0, 0);                               // tiles 0 (and 1) in flight
  if (nt > 1) {
    stage(64, 1);
    asm volatile("s_waitcnt vmcnt(4) lgkmcnt(0)" ::: "memory");  // tile 0 done
  } else {
    asm volatile("s_waitcnt vmcnt(0) lgkmcnt(0)" ::: "memory");
  }
  __builtin_amdgcn_s_barrier();
  __builtin_amdgcn_sched_barrier(0);

  int cur = 0, sl2 = 2;                      // slot of tile ti, slot of ti+2
  for (int ti = 0; ti < nt; ++ti) {
    const int kv0 = ti * 64;
    const bool pre = (ti + 2 < nt);
    if (pre) stage((ti + 2) * 64, sl2);      // overlaps this whole iteration

    // ---- QK^T (swapped: S^T = K . Q^T)
    f32x4 s[4];
#pragma unroll
    for (int i = 0; i < 4; ++i) s[i] = f32x4{0.f, 0.f, 0.f, 0.f};
    __builtin_amdgcn_s_setprio(1);
#pragma unroll
    for (int kf = 0; kf < 2; ++kf) {
#pragma unroll
      for (int nf = 0; nf < 4; ++nf) {
        const int row = nf * 16 + lr;
        const int col = (kf * 32 + lg * 8) ^ ((row & 7) << 3);
        const bf16x8 kb = ld_bf8(&Kb[cur][row * 64 + col]);
        s[nf] = __builtin_amdgcn_mfma_f32_16x16x32_bf16(kb, qf[kf], s[nf], 0, 0, 0);
      }
    }
    // ---- PV of PREVIOUS tile (register operands; overlaps softmax below)
    if (ti > 0) {
#pragma unroll
      for (int kf = 0; kf < 2; ++kf)
#pragma unroll
        for (int df = 0; df < 4; ++df)
          oacc[df] = __builtin_amdgcn_mfma_f32_16x16x32_bf16(vbp[kf][df], pap[kf], oacc[df], 0, 0, 0);
    }
    __builtin_amdgcn_s_setprio(0);

    // ---- this tile's V frags -> registers (consumed next iteration)
#pragma unroll
    for (int kf = 0; kf < 2; ++kf)
#pragma unroll
      for (int df = 0; df < 4; ++df) {
        const int vrow = df * 16 + lr;
        const int vcol = (kf * 32 + lg * 8) ^ ((vrow & 7) << 3);
        vbp[kf][df] = ld_bf8(&Vb[cur][vrow * 64 + vcol]);
      }

    // ---- softmax (no cross-lane ops on common path)
    if (ti == qt) {                          // diagonal tile: causal mask
#pragma unroll
      for (int nf = 0; nf < 4; ++nf) {
        const int kv = kv0 + nf * 16 + 4 * lg;
#pragma unroll
        for (int r = 0; r < 4; ++r)
          if (kv + r > qb + lr) s[nf][r] = -3e38f;
      }
    }
    float m01 = -3e38f, m23 = -3e38f;        // balanced per-lane max tree
#pragma unroll
    for (int r = 0; r < 4; ++r) {
      m01 = fmaxf(m01, fmaxf(s[0][r], s[1][r]));
      m23 = fmaxf(m23, fmaxf(s[2][r], s[3][r]));
    }
    const float mx = fmaxf(m01, m23);
    if (!__all(mx <= mrun + 8.f)) {          // defer-max (T13); rare branch
      float m0 = fmaxf(mx, __shfl_xor(mx, 16));
      m0 = fmaxf(m0, __shfl_xor(m0, 32));
      const float n0 = fmaxf(mrun, m0);
      const float c0 = __builtin_amdgcn_exp2f(mrun - n0);
      mrun = n0;
      lpart *= c0;
#pragma unroll
      for (int df = 0; df < 4; ++df)
#pragma unroll
        for (int r = 0; r < 4; ++r) oacc[df][r] *= c0;
    }
    float rs[4] = {0.f, 0.f, 0.f, 0.f};      // 4 independent partial sums
#pragma unroll
    for (int nf = 0; nf < 4; ++nf)
#pragma unroll
      for (int r = 0; r < 4; ++r) {
        const float p = __builtin_amdgcn_exp2f(s[nf][r] - mrun);
        s[nf][r] = p;
        rs[nf] += p;
      }
    lpart += (rs[0] + rs[1]) + (rs[2] + rs[3]);

    // ---- pack P^T into PV B-operand fragments (in registers)
    unsigned wpk[4][2];
#pragma unroll
    for (int nf = 0; nf < 4; ++nf) {
      asm("v_cvt_pk_bf16_f32 %0, %1, %2" : "=v"(wpk[nf][0]) : "v"(s[nf][0]), "v"(s[nf][1]));
      asm("v_cvt_pk_bf16_f32 %0, %1, %2" : "=v"(wpk[nf][1]) : "v"(s[nf][2]), "v"(s[nf][3]));
    }
#pragma unroll
    for (int kf = 0; kf < 2; ++kf) {
      const unsigned a0w = __shfl(wpk[2 * kf][0], sl0), b0w = __shfl(wpk[2 * kf + 1][0], sl0);
      const unsigned a1w = __shfl(wpk[2 * kf][1], sl0), b1w = __shfl(wpk[2 * kf + 1][1], sl0);
      const unsigned a2w = __shfl(wpk[2 * kf][0], sl1), b2w = __shfl(wpk[2 * kf + 1][0], sl1);
      const unsigned a3w = __shfl(wpk[2 * kf][1], sl1), b3w = __shfl(wpk[2 * kf + 1][1], sl1);
      u32x4 uu;
      uu[0] = hi2 ? b0w : a0w;
      uu[1] = hi2 ? b1w : a1w;
      uu[2] = hi2 ? b2w : a2w;
      uu[3] = hi2 ? b3w : a3w;
      pap[kf] = __builtin_bit_cast(bf16x8, uu);
    }

    // ---- tile boundary: counted wait (T4). pre: tile t+1's 4 loads done,
    // t+2's 4 may stay in flight. No-pre: drain all. lgkmcnt(0): vbp reads
    // complete before any wave can overwrite this slot (reused at t+3).
    if (pre) asm volatile("s_waitcnt vmcnt(4) lgkmcnt(0)" ::: "memory");
    else     asm volatile("s_waitcnt vmcnt(0) lgkmcnt(0)" ::: "memory");
    __builtin_amdgcn_s_barrier();
    __builtin_amdgcn_sched_barrier(0);
    cur = (cur == 2) ? 0 : cur + 1;
    sl2 = (sl2 == 2) ? 0 : sl2 + 1;
  }

  // ---- final PV (last tile)
#pragma unroll
  for (int kf = 0; kf < 2; ++kf)
#pragma unroll
    for (int df = 0; df < 4; ++df)
      oacc[df] = __builtin_amdgcn_mfma_f32_16x16x32_bf16(vbp[kf][df], pap[kf], oacc[df], 0, 0, 0);

  float ls = lpart;
  ls += __shfl_xor(ls, 16);
  ls += __shfl_xor(ls, 32);
  const float inv = 1.f / ls;
  const int q = qb + lr;
#pragma unroll
  for (int df = 0; df < 4; ++df) {
    ushort4 o4;
    o4.x = bfc(oacc[df][0] * inv);
    o4.y = bfc(oacc[df][1] * inv);
    o4.z = bfc(oacc[df][2] * inv);
    o4.w = bfc(oacc[df][3] * inv);
    *reinterpret_cast<ushort4*>(
        &Ob[((size_t)(b * 2048 + q)) * 1024 + h * 64 + df * 16 + 4 * lg]) = o4;
  }
}

// ------------------------------------------------------------------ launch
extern "C" void kernel_launch(void* const* d_in, const int* in_sizes, int n_in,
                              void* d_out, int out_size, void* d_ws, size_t ws_size,
                              hipStream_t stream) {
  const float* x  = (const float*)d_in[0];
  const float* Wq = (const float*)d_in[1];
  const float* bq = (const float*)d_in[2];
  const float* Wk = (const float*)d_in[3];
  const float* bk = (const float*)d_in[4];
  const float* Wv = (const float*)d_in[5];
  const float* bv = (const float*)d_in[6];
  const float* Wo = (const float*)d_in[7];
  const float* bo = (const float*)d_in[8];
  float* out = (float*)d_out;

  unsigned short* xb  = (unsigned short*)d_ws;          // 4096*1024
  unsigned short* wqt = xb  + 4096 * 1024;              // 1024*1024 each
  unsigned short* wkt = wqt + 1024 * 1024;
  unsigned short* wvt = wkt + 1024 * 1024;
  unsigned short* wot = wvt + 1024 * 1024;
  unsigned short* Qh  = wot + 1024 * 1024;              // [b,h,s,d]
  unsigned short* Kh  = Qh  + 4096 * 1024;
  unsigned short* Vh  = Kh  + 4096 * 1024;              // (unused)
  unsigned short* Vt  = Vh  + 4096 * 1024;              // [b,h,d,s]
  unsigned short* Ob  = Vt  + 4096 * 1024;              // [4096][1024]

  prep_kernel<<<5120, 256, 0, stream>>>(x, Wq, Wk, Wv, Wo, xb, wqt, wkt, wvt, wot);
  gemm_qkv<<<dim3(32, 24), 256, 0, stream>>>(xb, wqt, wkt, wvt, bq, bk, bv,
                                             Qh, Kh, Vt);
  attn_kernel<<<1024, 256, 0, stream>>>(Qh, Kh, Vt, Ob);
  gemm_out<<<dim3(64, 8), 256, 0, stream>>>(Ob, wot, bo, out);
}

// Round 16
// 110.277 us; speedup vs baseline: 1.0096x; 1.0096x over previous
//
#include <hip/hip_runtime.h>

// Masked causal MHA: B=2, S=2048, E=1024, H=16, D=64.
// ws layout (bf16/ushort): xb[4096*1024] | wqt|wkt|wvt|wot[1024*1024 each, [N][K]]
//   | Qh|Kh|Vh(unused) [b,h,s,d] | Vt [b,h,d,s] | Ob [4096][1024].

using f32x4  = __attribute__((ext_vector_type(4))) float;
using bf16x8 = __attribute__((ext_vector_type(8))) __bf16;
using u16x8  = __attribute__((ext_vector_type(8))) unsigned short;
using u32x4  = __attribute__((ext_vector_type(4))) unsigned int;

__device__ __forceinline__ unsigned short f2bf(float f) {
  unsigned u = __float_as_uint(f);
  u += 0x7fff + ((u >> 16) & 1u);            // round-to-nearest-even
  return (unsigned short)(u >> 16);
}

__device__ __forceinline__ unsigned short bfc(float f) {   // HW cvt
  __bf16 h = (__bf16)f;
  return __builtin_bit_cast(unsigned short, h);
}

__device__ __forceinline__ bf16x8 ld_bf8(const unsigned short* p) {
  return __builtin_bit_cast(bf16x8, *reinterpret_cast<const u16x8*>(p));
}

#define GLDS16(gp, lp)                                                        \
  __builtin_amdgcn_global_load_lds(                                           \
      (__attribute__((address_space(1))) void*)(gp),                          \
      (__attribute__((address_space(3))) void*)(lp), 16, 0, 0)

// ------------------------------------------- prep: cast x + transpose weights
// blocks 0..4095: cast x -> bf16. blocks 4096..5119: W[k][n] -> Wt[n][k] bf16.
__global__ void prep_kernel(const float* __restrict__ x,
                            const float* __restrict__ w0, const float* __restrict__ w1,
                            const float* __restrict__ w2, const float* __restrict__ w3,
                            unsigned short* __restrict__ xb,
                            unsigned short* __restrict__ t0, unsigned short* __restrict__ t1,
                            unsigned short* __restrict__ t2, unsigned short* __restrict__ t3) {
  __shared__ float tile[64][65];
  const int t = threadIdx.x;
  const int bid = blockIdx.x;
  if (bid < 4096) {
    const int i = (bid * 256 + t) * 4;
    const float4 v = *reinterpret_cast<const float4*>(x + i);
    ushort4 o;
    o.x = f2bf(v.x); o.y = f2bf(v.y); o.z = f2bf(v.z); o.w = f2bf(v.w);
    *reinterpret_cast<ushort4*>(xb + i) = o;
    return;
  }
  const int q0 = bid - 4096;
  const int wsel = q0 >> 8, rem = q0 & 255;
  const float* src; unsigned short* dst;
  switch (wsel) {
    case 0:  src = w0; dst = t0; break;
    case 1:  src = w1; dst = t1; break;
    case 2:  src = w2; dst = t2; break;
    default: src = w3; dst = t3; break;
  }
  const int n0 = (rem & 15) * 64, k0 = (rem >> 4) * 64;
#pragma unroll
  for (int i = 0; i < 4; ++i) {               // load 64x64 fp32 tile, rows = k
    const int q = t + i * 256, r = q >> 4, c4 = q & 15;
    const float4 v = *reinterpret_cast<const float4*>(src + (k0 + r) * 1024 + n0 + c4 * 4);
    tile[r][c4 * 4 + 0] = v.x; tile[r][c4 * 4 + 1] = v.y;
    tile[r][c4 * 4 + 2] = v.z; tile[r][c4 * 4 + 3] = v.w;
  }
  __syncthreads();
#pragma unroll
  for (int i = 0; i < 4; ++i) {               // write Wt[n][k] bf16
    const int q = t + i * 256, n = q >> 4, c4 = q & 15;
    ushort4 o;
    o.x = f2bf(tile[c4 * 4 + 0][n]); o.y = f2bf(tile[c4 * 4 + 1][n]);
    o.z = f2bf(tile[c4 * 4 + 2][n]); o.w = f2bf(tile[c4 * 4 + 3][n]);
    *reinterpret_cast<ushort4*>(dst + (n0 + n) * 1024 + k0 + c4 * 4) = o;
  }
}

// ------------------------------------------------------------ QKV GEMM
// C[4096][N] = xb @ Wt^T (+ bias). 128x128 tile, BK=64, 4 waves of 64x64.
// Q scaled by 0.125*log2e -> [b,h,s,d]; K -> [b,h,s,d]; V -> Vt [b,h,d,s].
// launch_bounds(256,3): cap VGPR so 3 blocks/CU stay resident (768-block grid).
__global__ __launch_bounds__(256, 3) void gemm_qkv(
    const unsigned short* __restrict__ A,
    const unsigned short* __restrict__ BtQ, const unsigned short* __restrict__ BtK,
    const unsigned short* __restrict__ BtV,
    const float* __restrict__ biasQ, const float* __restrict__ biasK,
    const float* __restrict__ biasV,
    unsigned short* __restrict__ OQ, unsigned short* __restrict__ OK_,
    unsigned short* __restrict__ OVt) {
  __shared__ unsigned short As[128 * 64];
  __shared__ unsigned short Bs[128 * 64];

  const int mt = blockIdx.x, nt = blockIdx.y;
  const int which = nt >> 3;
  const int nloc0 = (nt & 7) * 128;
  const unsigned short* Bt = (which == 0) ? BtQ : (which == 1) ? BtK : BtV;
  const float* bias = (which == 0) ? biasQ : (which == 1) ? biasK : biasV;
  const int m0 = mt * 128;
  const int t = threadIdx.x;
  const int w = t >> 6, l = t & 63;
  const int wm = (w >> 1) * 64, wn = (w & 1) * 64;
  const int lr = l & 15, lg = l >> 4;

  f32x4 acc[4][4];
#pragma unroll
  for (int i = 0; i < 4; ++i)
#pragma unroll
    for (int j = 0; j < 4; ++j) acc[i][j] = f32x4{0.f, 0.f, 0.f, 0.f};

  for (int k0 = 0; k0 < 1024; k0 += 64) {
#pragma unroll
    for (int i = 0; i < 4; ++i) {             // stage A tile: [128 m][64 k]
      const int off = t * 16 + i * 4096;
      const int r = off >> 7, cb = off & 127;
      GLDS16(A + (m0 + r) * 1024 + k0 + (cb >> 1), ((char*)As) + off);
    }
#pragma unroll
    for (int i = 0; i < 4; ++i) {             // stage B tile: [128 n][64 k]
      const int off = t * 16 + i * 4096;
      const int r = off >> 7, cb = off & 127;
      GLDS16(Bt + (nloc0 + r) * 1024 + k0 + (cb >> 1), ((char*)Bs) + off);
    }
    __syncthreads();
#pragma unroll
    for (int kk = 0; kk < 2; ++kk) {
      bf16x8 af[4], bfr[4];
#pragma unroll
      for (int mi = 0; mi < 4; ++mi)
        af[mi] = ld_bf8(As + (wm + mi * 16 + lr) * 64 + kk * 32 + lg * 8);
#pragma unroll
      for (int ni = 0; ni < 4; ++ni)
        bfr[ni] = ld_bf8(Bs + (wn + ni * 16 + lr) * 64 + kk * 32 + lg * 8);
#pragma unroll
      for (int mi = 0; mi < 4; ++mi)
#pragma unroll
        for (int ni = 0; ni < 4; ++ni)
          acc[mi][ni] = __builtin_amdgcn_mfma_f32_16x16x32_bf16(af[mi], bfr[ni], acc[mi][ni], 0, 0, 0);
    }
    __syncthreads();
  }

  const float scl = (which == 0) ? 0.18033688f : 1.0f;   // 0.125*log2(e) for Q
#pragma unroll
  for (int ni = 0; ni < 4; ++ni) {
    const int n = nloc0 + wn + ni * 16 + lr;  // column within this weight
    const float bv = bias[n];
    const int hh = n >> 6, dd = n & 63;
#pragma unroll
    for (int mi = 0; mi < 4; ++mi) {
      const int mB = m0 + wm + mi * 16 + 4 * lg;
      const int bb = mB >> 11, sloc = mB & 2047;
      if (which == 2) {                       // V -> Vt [b,h,d,s], 8B stores
        ushort4 o4;
        o4.x = bfc(acc[mi][ni][0] + bv);
        o4.y = bfc(acc[mi][ni][1] + bv);
        o4.z = bfc(acc[mi][ni][2] + bv);
        o4.w = bfc(acc[mi][ni][3] + bv);
        *reinterpret_cast<ushort4*>(
            &OVt[(((size_t)(bb * 16 + hh)) * 64 + dd) * 2048 + sloc]) = o4;
      } else {
        unsigned short* Oqk = (which == 0) ? OQ : OK_;
#pragma unroll
        for (int r = 0; r < 4; ++r) {
          const float v = (acc[mi][ni][r] + bv) * scl;
          Oqk[(((size_t)(bb * 16 + hh)) * 2048 + sloc + r) * 64 + dd] = f2bf(v);
        }
      }
    }
  }
}

// ------------------------------------------------------- output-proj GEMM
// C[4096][1024] = Ob @ Wot^T + bo (fp32). 64x128 tile -> 512 blocks (2/CU).
__global__ __launch_bounds__(256, 2) void gemm_out(
    const unsigned short* __restrict__ A, const unsigned short* __restrict__ Bt,
    const float* __restrict__ bias, float* __restrict__ OF) {
  __shared__ unsigned short As[64 * 64];     // 8 KB
  __shared__ unsigned short Bs[128 * 64];    // 16 KB

  const int m0 = blockIdx.x * 64;
  const int nloc0 = blockIdx.y * 128;
  const int t = threadIdx.x;
  const int w = t >> 6, l = t & 63;
  const int wm = (w >> 1) * 32, wn = (w & 1) * 64;
  const int lr = l & 15, lg = l >> 4;

  f32x4 acc[2][4];
#pragma unroll
  for (int i = 0; i < 2; ++i)
#pragma unroll
    for (int j = 0; j < 4; ++j) acc[i][j] = f32x4{0.f, 0.f, 0.f, 0.f};

  for (int k0 = 0; k0 < 1024; k0 += 64) {
#pragma unroll
    for (int i = 0; i < 2; ++i) {             // stage A tile: [64 m][64 k]
      const int off = t * 16 + i * 4096;
      const int r = off >> 7, cb = off & 127;
      GLDS16(A + (m0 + r) * 1024 + k0 + (cb >> 1), ((char*)As) + off);
    }
#pragma unroll
    for (int i = 0; i < 4; ++i) {             // stage B tile: [128 n][64 k]
      const int off = t * 16 + i * 4096;
      const int r = off >> 7, cb = off & 127;
      GLDS16(Bt + (nloc0 + r) * 1024 + k0 + (cb >> 1), ((char*)Bs) + off);
    }
    __syncthreads();
#pragma unroll
    for (int kk = 0; kk < 2; ++kk) {
      bf16x8 af[2], bfr[4];
#pragma unroll
      for (int mi = 0; mi < 2; ++mi)
        af[mi] = ld_bf8(As + (wm + mi * 16 + lr) * 64 + kk * 32 + lg * 8);
#pragma unroll
      for (int ni = 0; ni < 4; ++ni)
        bfr[ni] = ld_bf8(Bs + (wn + ni * 16 + lr) * 64 + kk * 32 + lg * 8);
#pragma unroll
      for (int mi = 0; mi < 2; ++mi)
#pragma unroll
        for (int ni = 0; ni < 4; ++ni)
          acc[mi][ni] = __builtin_amdgcn_mfma_f32_16x16x32_bf16(af[mi], bfr[ni], acc[mi][ni], 0, 0, 0);
    }
    __syncthreads();
  }

#pragma unroll
  for (int ni = 0; ni < 4; ++ni) {
    const int n = nloc0 + wn + ni * 16 + lr;
    const float bv = bias[n];
#pragma unroll
    for (int mi = 0; mi < 2; ++mi) {
#pragma unroll
      for (int r = 0; r < 4; ++r) {
        const int m = m0 + wm + mi * 16 + 4 * lg + r;
        OF[m * 1024 + n] = acc[mi][ni][r] + bv;
      }
    }
  }
}

// ------------------------------------------------------- flash attention v6
// (R9/R14-proven session best) 64-row q-blocks, 4 waves, 1024 blocks, LPT.
// Swapped QK^T, in-register softmax, defer-max, per-lane partial l, PV lags
// one tile via register V/P frags. K+V LDS dbuf with XOR swizzle.
__global__ __launch_bounds__(256, 4) void attn_kernel(
    const unsigned short* __restrict__ Qh, const unsigned short* __restrict__ Kh,
    const unsigned short* __restrict__ Vt, unsigned short* __restrict__ Ob) {
  const int g = blockIdx.x;
  const int qt = 31 - (g >> 5);              // LPT: longest first
  const int bh = g & 31;
  const int b = bh >> 4, h = bh & 15;
  const int t = threadIdx.x, w = t >> 6, l = t & 63;
  const int lr = l & 15, lg = l >> 4;
  const int sl0 = lr + 32 * (lg & 1);        // pack-shuffle source lanes
  const int sl1 = sl0 + 16;
  const bool hi2 = (l & 32) != 0;

  __shared__ unsigned short Kb[2][4096];     // [64 kv][64 d], swizzled
  __shared__ unsigned short Vb[2][4096];     // [64 d][64 kv], swizzled

  const unsigned short* Kbase = Kh + (size_t)bh * (2048 * 64);
  const unsigned short* Vbase = Vt + (size_t)bh * (64 * 2048);

  const int qb = qt * 64 + w * 16;           // this wave's 16 q rows
  const unsigned short* Qp = Qh + ((size_t)bh * 2048 + qb + lr) * 64;
  bf16x8 qf[2];
  qf[0] = ld_bf8(Qp + lg * 8);
  qf[1] = ld_bf8(Qp + 32 + lg * 8);

  f32x4 oacc[4];                             // O^T: lane q=qb+lr, d=df*16+4lg+r
#pragma unroll
  for (int i = 0; i < 4; ++i) oacc[i] = f32x4{0.f, 0.f, 0.f, 0.f};
  float mrun = -3e38f;
  float lpart = 0.f;                         // per-lane partial denominator

  bf16x8 vbp[2][4];                          // V frags of previous tile
  bf16x8 pap[2];                             // P frags of previous tile

  auto stage = [&](int kv0, int bi) {
#pragma unroll
    for (int p = 0; p < 2; ++p) {
      const int o = t * 16 + p * 4096;       // linear byte offset in 8KB tile
      const int row = o >> 7;
      const int scb = (o & 127) ^ ((row & 7) << 4);   // pre-swizzled src col
      GLDS16(Kbase + (size_t)(kv0 + row) * 64 + (scb >> 1), ((char*)Kb[bi]) + o);
      GLDS16(Vbase + (size_t)row * 2048 + kv0 + (scb >> 1), ((char*)Vb[bi]) + o);
    }
  };

  const int nt = qt + 1;
  stage(0, 0);
  __syncthreads();

  for (int ti = 0; ti < nt; ++ti) {
    const int cur = ti & 1;
    const int kv0 = ti * 64;
    if (ti + 1 < nt) stage((ti + 1) * 64, cur ^ 1);

    // ---- QK^T (swapped: S^T = K . Q^T)
    f32x4 s[4];
#pragma unroll
    for (int i = 0; i < 4; ++i) s[i] = f32x4{0.f, 0.f, 0.f, 0.f};
    __builtin_amdgcn_s_setprio(1);
#pragma unroll
    for (int kf = 0; kf < 2; ++kf) {
#pragma unroll
      for (int nf = 0; nf < 4; ++nf) {
        const int row = nf * 16 + lr;
        const int col = (kf * 32 + lg * 8) ^ ((row & 7) << 3);
        const bf16x8 kb = ld_bf8(&Kb[cur][row * 64 + col]);
        s[nf] = __builtin_amdgcn_mfma_f32_16x16x32_bf16(kb, qf[kf], s[nf], 0, 0, 0);
      }
    }
    // ---- PV of PREVIOUS tile (register operands; overlaps softmax below)
    if (ti > 0) {
#pragma unroll
      for (int kf = 0; kf < 2; ++kf)
#pragma unroll
        for (int df = 0; df < 4; ++df)
          oacc[df] = __builtin_amdgcn_mfma_f32_16x16x32_bf16(vbp[kf][df], pap[kf], oacc[df], 0, 0, 0);
    }
    __builtin_amdgcn_s_setprio(0);

    // ---- this tile's V frags -> registers (consumed next iteration)
#pragma unroll
    for (int kf = 0; kf < 2; ++kf)
#pragma unroll
      for (int df = 0; df < 4; ++df) {
        const int vrow = df * 16 + lr;
        const int vcol = (kf * 32 + lg * 8) ^ ((vrow & 7) << 3);
        vbp[kf][df] = ld_bf8(&Vb[cur][vrow * 64 + vcol]);
      }

    // ---- softmax (no cross-lane ops on common path)
    if (ti == qt) {                          // diagonal tile: causal mask
#pragma unroll
      for (int nf = 0; nf < 4; ++nf) {
        const int kv = kv0 + nf * 16 + 4 * lg;
#pragma unroll
        for (int r = 0; r < 4; ++r)
          if (kv + r > qb + lr) s[nf][r] = -3e38f;
      }
    }
    float m01 = -3e38f, m23 = -3e38f;        // balanced per-lane max tree
#pragma unroll
    for (int r = 0; r < 4; ++r) {
      m01 = fmaxf(m01, fmaxf(s[0][r], s[1][r]));
      m23 = fmaxf(m23, fmaxf(s[2][r], s[3][r]));
    }
    const float mx = fmaxf(m01, m23);
    if (!__all(mx <= mrun + 8.f)) {          // defer-max (T13); rare branch
      float m0 = fmaxf(mx, __shfl_xor(mx, 16));
      m0 = fmaxf(m0, __shfl_xor(m0, 32));
      const float n0 = fmaxf(mrun, m0);
      const float c0 = __builtin_amdgcn_exp2f(mrun - n0);
      mrun = n0;
      lpart *= c0;
#pragma unroll
      for (int df = 0; df < 4; ++df)
#pragma unroll
        for (int r = 0; r < 4; ++r) oacc[df][r] *= c0;
    }
    float rs[4] = {0.f, 0.f, 0.f, 0.f};      // 4 independent partial sums
#pragma unroll
    for (int nf = 0; nf < 4; ++nf)
#pragma unroll
      for (int r = 0; r < 4; ++r) {
        const float p = __builtin_amdgcn_exp2f(s[nf][r] - mrun);
        s[nf][r] = p;
        rs[nf] += p;
      }
    lpart += (rs[0] + rs[1]) + (rs[2] + rs[3]);

    // ---- pack P^T into PV B-operand fragments (in registers)
    unsigned wpk[4][2];
#pragma unroll
    for (int nf = 0; nf < 4; ++nf) {
      asm("v_cvt_pk_bf16_f32 %0, %1, %2" : "=v"(wpk[nf][0]) : "v"(s[nf][0]), "v"(s[nf][1]));
      asm("v_cvt_pk_bf16_f32 %0, %1, %2" : "=v"(wpk[nf][1]) : "v"(s[nf][2]), "v"(s[nf][3]));
    }
#pragma unroll
    for (int kf = 0; kf < 2; ++kf) {
      const unsigned a0w = __shfl(wpk[2 * kf][0], sl0), b0w = __shfl(wpk[2 * kf + 1][0], sl0);
      const unsigned a1w = __shfl(wpk[2 * kf][1], sl0), b1w = __shfl(wpk[2 * kf + 1][1], sl0);
      const unsigned a2w = __shfl(wpk[2 * kf][0], sl1), b2w = __shfl(wpk[2 * kf + 1][0], sl1);
      const unsigned a3w = __shfl(wpk[2 * kf][1], sl1), b3w = __shfl(wpk[2 * kf + 1][1], sl1);
      u32x4 uu;
      uu[0] = hi2 ? b0w : a0w;
      uu[1] = hi2 ? b1w : a1w;
      uu[2] = hi2 ? b2w : a2w;
      uu[3] = hi2 ? b3w : a3w;
      pap[kf] = __builtin_bit_cast(bf16x8, uu);
    }
    __syncthreads();                         // drains prefetch + guards buffers
  }

  // ---- final PV (last tile)
#pragma unroll
  for (int kf = 0; kf < 2; ++kf)
#pragma unroll
    for (int df = 0; df < 4; ++df)
      oacc[df] = __builtin_amdgcn_mfma_f32_16x16x32_bf16(vbp[kf][df], pap[kf], oacc[df], 0, 0, 0);

  float ls = lpart;
  ls += __shfl_xor(ls, 16);
  ls += __shfl_xor(ls, 32);
  const float inv = 1.f / ls;
  const int q = qb + lr;
#pragma unroll
  for (int df = 0; df < 4; ++df) {
    ushort4 o4;
    o4.x = bfc(oacc[df][0] * inv);
    o4.y = bfc(oacc[df][1] * inv);
    o4.z = bfc(oacc[df][2] * inv);
    o4.w = bfc(oacc[df][3] * inv);
    *reinterpret_cast<ushort4*>(
        &Ob[((size_t)(b * 2048 + q)) * 1024 + h * 64 + df * 16 + 4 * lg]) = o4;
  }
}

// ------------------------------------------------------------------ launch
extern "C" void kernel_launch(void* const* d_in, const int* in_sizes, int n_in,
                              void* d_out, int out_size, void* d_ws, size_t ws_size,
                              hipStream_t stream) {
  const float* x  = (const float*)d_in[0];
  const float* Wq = (const float*)d_in[1];
  const float* bq = (const float*)d_in[2];
  const float* Wk = (const float*)d_in[3];
  const float* bk = (const float*)d_in[4];
  const float* Wv = (const float*)d_in[5];
  const float* bv = (const float*)d_in[6];
  const float* Wo = (const float*)d_in[7];
  const float* bo = (const float*)d_in[8];
  float* out = (float*)d_out;

  unsigned short* xb  = (unsigned short*)d_ws;          // 4096*1024
  unsigned short* wqt = xb  + 4096 * 1024;              // 1024*1024 each
  unsigned short* wkt = wqt + 1024 * 1024;
  unsigned short* wvt = wkt + 1024 * 1024;
  unsigned short* wot = wvt + 1024 * 1024;
  unsigned short* Qh  = wot + 1024 * 1024;              // [b,h,s,d]
  unsigned short* Kh  = Qh  + 4096 * 1024;
  unsigned short* Vh  = Kh  + 4096 * 1024;              // (unused)
  unsigned short* Vt  = Vh  + 4096 * 1024;              // [b,h,d,s]
  unsigned short* Ob  = Vt  + 4096 * 1024;              // [4096][1024]

  prep_kernel<<<5120, 256, 0, stream>>>(x, Wq, Wk, Wv, Wo, xb, wqt, wkt, wvt, wot);
  gemm_qkv<<<dim3(32, 24), 256, 0, stream>>>(xb, wqt, wkt, wvt, bq, bk, bv,
                                             Qh, Kh, Vt);
  attn_kernel<<<1024, 256, 0, stream>>>(Qh, Kh, Vt, Ob);
  gemm_out<<<dim3(64, 8), 256, 0, stream>>>(Ob, wot, bo, out);
}